// Round 4
// baseline (182.318 us; speedup 1.0000x reference)
//
#include <hip/hip_runtime.h>
#include <hip/hip_bf16.h>

// CrossLocal: B=4, C=64, CI=32, cross 64x64 (Nc=4096), main 128x128.
// R4: S^T-form MFMA flash attention (2x ds_write_b64 + 1x ds_read_b128 per
// chunk), true read-ahead pipelining, 32q blocks with 2-way key split.
// ws: Qb[bf16 4*4096*32] Kb[same] Vt[bf16 4*32*4096] out2[f32 4*64*4096] stats1[512]

typedef __attribute__((ext_vector_type(8))) short bf16x8;
typedef __attribute__((ext_vector_type(4))) float f32x4;

#define LOG2E 1.4426950408889634f

static __device__ __forceinline__ unsigned short f2bf_bits(float x) {
    __hip_bfloat16 h = __float2bfloat16(x);
    return *(unsigned short*)&h;
}
static __device__ __forceinline__ unsigned int pk2bf(float a, float b) {
    __hip_bfloat162 h = __float22bfloat162_rn(make_float2(a, b));
    return *(unsigned int*)&h;
}

// ---------------- Kernel 1: Q,K,V prep (bf16 out) ----------------
// kind: 0=Q (g, pre-scaled by log2e), 1=K (theta), 2=V (phi on 2x2-pooled main)
__global__ __launch_bounds__(256) void qkv_kernel(
    const float* __restrict__ cross, const float* __restrict__ mainf,
    const float* __restrict__ g_w,  const float* __restrict__ g_b,
    const float* __restrict__ th_w, const float* __restrict__ th_b,
    const float* __restrict__ ph_w, const float* __restrict__ ph_b,
    __hip_bfloat16* __restrict__ Qb, __hip_bfloat16* __restrict__ Kb,
    __hip_bfloat16* __restrict__ Vt)
{
    int gid  = blockIdx.x * 256 + threadIdx.x;   // 0..49151
    int kind = gid >> 14;                        // uniform per block
    int pix  = gid & 16383;
    int b = pix >> 12, n = pix & 4095;

    const float* w  = (kind == 0) ? g_w : (kind == 1) ? th_w : ph_w;
    const float* bs = (kind == 0) ? g_b : (kind == 1) ? th_b : ph_b;

    float acc[32];
#pragma unroll
    for (int ci = 0; ci < 32; ++ci) acc[ci] = bs[ci];

    if (kind < 2) {
        const float* cp = cross + (size_t)(b * 64) * 4096 + n;
        for (int c = 0; c < 64; ++c) {
            float xc = cp[(size_t)c * 4096];
#pragma unroll
            for (int ci = 0; ci < 32; ++ci)
                acc[ci] = fmaf(w[(ci << 6) + c], xc, acc[ci]);
        }
        if (kind == 0) {
#pragma unroll
            for (int ci = 0; ci < 32; ++ci) acc[ci] *= LOG2E;
        }
        unsigned int u[16];
#pragma unroll
        for (int i = 0; i < 16; ++i)
            u[i] = (unsigned int)f2bf_bits(acc[2 * i]) |
                   ((unsigned int)f2bf_bits(acc[2 * i + 1]) << 16);
        __hip_bfloat16* dst = ((kind == 0) ? Qb : Kb) + (size_t)pix * 32;
        uint4* d4 = (uint4*)dst;
#pragma unroll
        for (int r = 0; r < 4; ++r)
            d4[r] = make_uint4(u[4*r], u[4*r+1], u[4*r+2], u[4*r+3]);
    } else {
        int i = n >> 6, j = n & 63;
        const float* mp = mainf + (size_t)(b * 64) * 16384 + i * 256 + j * 2;
        for (int c = 0; c < 64; ++c) {
            const float* m = mp + (size_t)c * 16384;
            float xm = 0.25f * (m[0] + m[1] + m[128] + m[129]);
#pragma unroll
            for (int ci = 0; ci < 32; ++ci)
                acc[ci] = fmaf(w[(ci << 6) + c], xm, acc[ci]);
        }
#pragma unroll
        for (int ci = 0; ci < 32; ++ci)
            Vt[((size_t)((b << 5) | ci) << 12) + n] = __float2bfloat16(acc[ci]);
    }
}

// ---------------- Kernel 2: S^T-form MFMA flash attention + W conv ----------------
// grid (128 qtiles of 32, 4 batch) x 256 thr. Wave w: q-group w>>1 (16 q),
// key-half w&1 (2048 keys, 64 chunks of 32).
// S^T = mfma(A=K-frag, B=Q-frag): lane(c,lo) -> S[q=lo][key=k0+4c+r]: keys
// consecutive per lane -> pack 4 bf16 -> ds_write_b64 x2. PV reads A-frag of P
// via one ds_read_b128 issued one iteration ahead of use.
__global__ __launch_bounds__(256) void attn_mfma(
    const __hip_bfloat16* __restrict__ Qb, const __hip_bfloat16* __restrict__ Kb,
    const __hip_bfloat16* __restrict__ Vt, const float* __restrict__ w_w,
    const float* __restrict__ w_b, float* __restrict__ out2)
{
    __shared__ __align__(16) __hip_bfloat16 pbuf[4][2][16][40]; // stride 40: uniform banks, 16B-aligned rows
    __shared__ __align__(16) float redbuf[2][64][12];
    __shared__ __align__(16) float obuf[32][36];
    const int tid = threadIdx.x, lane = tid & 63, w = tid >> 6;
    const int lo = lane & 15, c = lane >> 4;
    const int kh = w & 1, qg = w >> 1;
    const int b = blockIdx.y;
    const int qbase = (blockIdx.x << 5) + (qg << 4);

    // Q fragment (B-operand of S^T; also exactly the A-operand layout of Q)
    const bf16x8 aq = *(const bf16x8*)(Qb + (((size_t)(b << 12) + qbase + lo) << 5) + (c << 3));
    const __hip_bfloat16* Kbb = Kb + ((size_t)(b << 12) << 5);
    const __hip_bfloat16* Vbb = Vt + ((size_t)(b << 5) << 12);

    f32x4 acc0 = {0.f,0.f,0.f,0.f}, acc1 = {0.f,0.f,0.f,0.f};
    float den = 0.f;
    const f32x4 z = {0.f,0.f,0.f,0.f};
    const int kq = kh << 11;
#define LDK(k)      (*(const bf16x8*)(Kbb + ((size_t)((k) + lo) << 5) + (c << 3)))
#define LDV(k, cio) (*(const bf16x8*)(Vbb + ((size_t)(lo + (cio)) << 12) + (k) + (c << 3)))

    bf16x8 k0c = LDK(kq),      k1c = LDK(kq + 16);
    bf16x8 vB0 = LDV(kq, 0),   vB1 = LDV(kq, 16);       // V(ch) for next iter's PV
    bf16x8 k0n = LDK(kq + 32), k1n = LDK(kq + 48);
    bf16x8 vN0 = LDV(kq + 32, 0), vN1 = LDV(kq + 32, 16);
    bf16x8 ap;                                          // P frag read last iter

    // ---- chunk 0: S phase + read-ahead ----
    {
        f32x4 s0 = __builtin_amdgcn_mfma_f32_16x16x32_bf16(k0c, aq, z, 0, 0, 0);
        f32x4 s1 = __builtin_amdgcn_mfma_f32_16x16x32_bf16(k1c, aq, z, 0, 0, 0);
        float p0 = __builtin_amdgcn_exp2f(s0[0]), p1 = __builtin_amdgcn_exp2f(s0[1]);
        float p2 = __builtin_amdgcn_exp2f(s0[2]), p3 = __builtin_amdgcn_exp2f(s0[3]);
        float q0 = __builtin_amdgcn_exp2f(s1[0]), q1 = __builtin_amdgcn_exp2f(s1[1]);
        float q2 = __builtin_amdgcn_exp2f(s1[2]), q3 = __builtin_amdgcn_exp2f(s1[3]);
        den += ((p0 + p1) + (p2 + p3)) + ((q0 + q1) + (q2 + q3));
        uint2 wv0 = make_uint2(pk2bf(p0, p1), pk2bf(p2, p3));
        uint2 wv1 = make_uint2(pk2bf(q0, q1), pk2bf(q2, q3));
        *(uint2*)&pbuf[w][0][lo][c << 2]        = wv0;
        *(uint2*)&pbuf[w][0][lo][16 + (c << 2)] = wv1;
        ap = *(const bf16x8*)&pbuf[w][0][lo][c << 3];   // read-ahead (FIFO after writes)
    }

#pragma unroll 2
    for (int ch = 1; ch < 64; ++ch) {
        const int kn = kq + ((ch + 1) & 63) * 32;
        bf16x8 vA0 = vB0, vA1 = vB1;          // V(ch-1) for this iter's PV
        vB0 = vN0; vB1 = vN1;                 // V(ch)
        k0c = k0n; k1c = k1n;                 // K(ch)
        k0n = LDK(kn); k1n = LDK(kn + 16);    // prefetch K(ch+1)
        vN0 = LDV(kn, 0); vN1 = LDV(kn, 16);  // prefetch V(ch+1)

        // S of chunk ch
        f32x4 s0 = __builtin_amdgcn_mfma_f32_16x16x32_bf16(k0c, aq, z, 0, 0, 0);
        f32x4 s1 = __builtin_amdgcn_mfma_f32_16x16x32_bf16(k1c, aq, z, 0, 0, 0);
        float p0 = __builtin_amdgcn_exp2f(s0[0]), p1 = __builtin_amdgcn_exp2f(s0[1]);
        float p2 = __builtin_amdgcn_exp2f(s0[2]), p3 = __builtin_amdgcn_exp2f(s0[3]);
        float q0 = __builtin_amdgcn_exp2f(s1[0]), q1 = __builtin_amdgcn_exp2f(s1[1]);
        float q2 = __builtin_amdgcn_exp2f(s1[2]), q3 = __builtin_amdgcn_exp2f(s1[3]);
        den += ((p0 + p1) + (p2 + p3)) + ((q0 + q1) + (q2 + q3));
        uint2 wv0 = make_uint2(pk2bf(p0, p1), pk2bf(p2, p3));
        uint2 wv1 = make_uint2(pk2bf(q0, q1), pk2bf(q2, q3));
        *(uint2*)&pbuf[w][ch & 1][lo][c << 2]        = wv0;
        *(uint2*)&pbuf[w][ch & 1][lo][16 + (c << 2)] = wv1;

        // PV of chunk ch-1 (ap read last iter -> latency fully hidden)
        acc0 = __builtin_amdgcn_mfma_f32_16x16x32_bf16(ap, vA0, acc0, 0, 0, 0);
        acc1 = __builtin_amdgcn_mfma_f32_16x16x32_bf16(ap, vA1, acc1, 0, 0, 0);

        // read-ahead P(ch) for next iter
        ap = *(const bf16x8*)&pbuf[w][ch & 1][lo][c << 3];
    }
    // tail: PV of chunk 63
    acc0 = __builtin_amdgcn_mfma_f32_16x16x32_bf16(ap, vB0, acc0, 0, 0, 0);
    acc1 = __builtin_amdgcn_mfma_f32_16x16x32_bf16(ap, vB1, acc1, 0, 0, 0);
#undef LDK
#undef LDV

    // intra-wave den reduction over c (lanes sharing lo): bits 4,5
    den += __shfl_xor(den, 16);
    den += __shfl_xor(den, 32);

    // cross-wave (key-half pair) combine: odd wave dumps, even wave adds
    if (kh) {
        f32x4* rb = (f32x4*)&redbuf[qg][lane][0];
        rb[0] = acc0; rb[1] = acc1;
        f32x4 dv = {den, 0.f, 0.f, 0.f};
        rb[2] = dv;
    }
    __syncthreads();
    if (kh == 0) {
        const f32x4* rb = (const f32x4*)&redbuf[qg][lane][0];
        f32x4 a0 = rb[0], a1 = rb[1], dv = rb[2];
        acc0 += a0; acc1 += a1;
        den += dv[0];
        // den holds total for q=lo; fetch den for q=4c+r from lane 4c+r
#pragma unroll
        for (int r = 0; r < 4; ++r) {
            float inv = 1.0f / __shfl(den, (c << 2) | r);
            obuf[(qg << 4) | (c << 2) | r][lo]      = acc0[r] * inv;
            obuf[(qg << 4) | (c << 2) | r][16 + lo] = acc1[r] * inv;
        }
    }
    __syncthreads();

    // ---- fused W 1x1 conv over the 32-query tile ----
    const int q = tid & 31, cog = tid >> 5;   // 8 co per thread
    float ov[32];
    const float4* orow = (const float4*)&obuf[q][0];
#pragma unroll
    for (int k4 = 0; k4 < 8; ++k4) {
        float4 t = orow[k4];
        ov[4*k4] = t.x; ov[4*k4+1] = t.y; ov[4*k4+2] = t.z; ov[4*k4+3] = t.w;
    }
    float* dstbase = out2 + (((size_t)(b << 6)) << 12) + (blockIdx.x << 5) + q;
#pragma unroll
    for (int kk = 0; kk < 8; ++kk) {
        int co = (kk << 3) | cog;
        const float4* wr = (const float4*)&w_w[co << 5];
        float acc = w_b[co];
#pragma unroll
        for (int k4 = 0; k4 < 8; ++k4) {
            float4 t = wr[k4];
            acc = fmaf(t.x, ov[4*k4],   acc);
            acc = fmaf(t.y, ov[4*k4+1], acc);
            acc = fmaf(t.z, ov[4*k4+2], acc);
            acc = fmaf(t.w, ov[4*k4+3], acc);
        }
        dstbase[(size_t)co << 12] = acc;
    }
}

// ---------------- Kernel 3: BN partial statistics (per channel, per batch) ----------------
__global__ __launch_bounds__(256) void stats_kernel(
    const float* __restrict__ out2, float* __restrict__ stats1)
{
    int co = blockIdx.x >> 2, b = blockIdx.x & 3, t = threadIdx.x;
    const float* p = out2 + ((size_t)((b << 6) | co) << 12);
    float s = 0.f, s2 = 0.f;
#pragma unroll
    for (int ii = 0; ii < 16; ++ii) {
        float v = p[(ii << 8) | t];
        s += v; s2 = fmaf(v, v, s2);
    }
    __shared__ float rs[256], rs2[256];
    rs[t] = s; rs2[t] = s2;
    __syncthreads();
    for (int off = 128; off > 0; off >>= 1) {
        if (t < off) { rs[t] += rs[t + off]; rs2[t] += rs2[t + off]; }
        __syncthreads();
    }
    if (t == 0) {
        stats1[blockIdx.x * 2]     = rs[0];
        stats1[blockIdx.x * 2 + 1] = rs2[0];
    }
}

// ---------------- Kernel 4: BN + bilinear 64->128 + residual ----------------
__global__ __launch_bounds__(256) void up_kernel(
    const float* __restrict__ out2, const float* __restrict__ stats1,
    const float* __restrict__ gamma, const float* __restrict__ beta,
    const float* __restrict__ mainf, float* __restrict__ out)
{
    int idx = blockIdx.x * 256 + threadIdx.x;   // < 4*64*128*128
    int j  = idx & 127;
    int i  = (idx >> 7) & 127;
    int co = (idx >> 14) & 63;            // uniform within a block
    int b  = idx >> 20;

    float sm = 0.f, sq = 0.f;
#pragma unroll
    for (int bb = 0; bb < 4; ++bb) {
        sm += stats1[((co << 2) | bb) * 2];
        sq += stats1[((co << 2) | bb) * 2 + 1];
    }
    float mean = sm * (1.0f / 16384.0f);
    float var  = sq * (1.0f / 16384.0f) - mean * mean;
    float inv  = rsqrtf(var + 1e-5f);
    float scale = gamma[co] * inv;
    float shift = beta[co] - mean * scale;

    int ih = i >> 1, il = j >> 1;
    int k0, k1; float wi;
    if (i & 1)       { k0 = ih;     k1 = (ih < 63) ? ih + 1 : 63; wi = 0.25f; }
    else if (ih == 0){ k0 = 0;      k1 = 0;                       wi = 0.0f;  }
    else             { k0 = ih - 1; k1 = ih;                      wi = 0.75f; }
    int l0, l1; float wj;
    if (j & 1)       { l0 = il;     l1 = (il < 63) ? il + 1 : 63; wj = 0.25f; }
    else if (il == 0){ l0 = 0;      l1 = 0;                       wj = 0.0f;  }
    else             { l0 = il - 1; l1 = il;                      wj = 0.75f; }

    const float* p = out2 + ((size_t)((b << 6) | co) << 12);
    float v00 = p[(k0 << 6) | l0], v01 = p[(k0 << 6) | l1];
    float v10 = p[(k1 << 6) | l0], v11 = p[(k1 << 6) | l1];
    float top = v00 + wj * (v01 - v00);
    float bot = v10 + wj * (v11 - v10);
    float v = top + wi * (bot - top);
    out[idx] = fmaf(v, scale, shift) + mainf[idx];
}

extern "C" void kernel_launch(void* const* d_in, const int* in_sizes, int n_in,
                              void* d_out, int out_size, void* d_ws, size_t ws_size,
                              hipStream_t stream)
{
    const float* mainf = (const float*)d_in[0];
    const float* cross = (const float*)d_in[1];
    const float* g_w   = (const float*)d_in[2];
    const float* g_b   = (const float*)d_in[3];
    const float* th_w  = (const float*)d_in[4];
    const float* th_b  = (const float*)d_in[5];
    const float* ph_w  = (const float*)d_in[6];
    const float* ph_b  = (const float*)d_in[7];
    const float* w_w   = (const float*)d_in[8];
    const float* w_b   = (const float*)d_in[9];
    const float* gamma = (const float*)d_in[10];
    const float* beta  = (const float*)d_in[11];
    float* out = (float*)d_out;

    __hip_bfloat16* Qb = (__hip_bfloat16*)d_ws;     // 4*4096*32
    __hip_bfloat16* Kb = Qb + 524288;
    __hip_bfloat16* Vt = Kb + 524288;               // [b][ci][4096]
    float* out2   = (float*)(Vt + 524288);          // 4*64*4096
    float* stats1 = out2 + 1048576;                 // 512

    qkv_kernel<<<192, 256, 0, stream>>>(cross, mainf, g_w, g_b, th_w, th_b,
                                        ph_w, ph_b, Qb, Kb, Vt);
    attn_mfma<<<dim3(128, 4), 256, 0, stream>>>(Qb, Kb, Vt, w_w, w_b, out2);
    stats_kernel<<<256, 256, 0, stream>>>(out2, stats1);
    up_kernel<<<16384, 256, 0, stream>>>(out2, stats1, gamma, beta, mainf, out);
}